// Round 19
// baseline (230.249 us; speedup 1.0000x reference)
//
#include <hip/hip_runtime.h>
#include <math.h>

// Swin block R19: R18 + double-buffered global_load_lds weight prefetch in the
// MLP loop (counted vmcnt, zero VGPR cost). 1 wave/window, zero barriers.
// B=64, H=W=56, C=96, WS=7, SS=3, NH=3, HD=32, N=49 (padded 64), nW=64.

#define CDIM 96
#define SCALE_QK 0.17677669529663687f  // 32^-0.5

typedef __attribute__((ext_vector_type(8))) short bf16x8;
typedef __attribute__((ext_vector_type(4))) float f32x4;
typedef __attribute__((ext_vector_type(2))) unsigned int u32x2;
typedef __attribute__((ext_vector_type(4))) unsigned int u32x4;

__device__ inline unsigned short f2b(float f) {
    union { float f; unsigned u; } v; v.f = f;
    unsigned r = v.u + 0x7FFF + ((v.u >> 16) & 1);   // RNE
    return (unsigned short)(r >> 16);
}
__device__ inline unsigned pkcvt(float a, float b) {   // low16=bf16(a), high16=bf16(b)
    unsigned d;
    asm("v_cvt_pk_bf16_f32 %0, %1, %2" : "=v"(d) : "v"(a), "v"(b));
    return d;
}
__device__ inline float bitsf(unsigned u) {
    union { unsigned u; float f; } v; v.u = u; return v.f;
}
__device__ inline bf16x8 mk8(unsigned d0, unsigned d1, unsigned d2, unsigned d3) {
    union { u32x4 u; bf16x8 h; } v;
    v.u = (u32x4){d0, d1, d2, d3};
    return v.h;
}
__device__ inline bf16x8 sel8(bool c, bf16x8 a, bf16x8 b) {   // c ? a : b per dword
    union { bf16x8 h; u32x4 u; } A, B, R;
    A.h = a; B.h = b;
    R.u.x = c ? A.u.x : B.u.x;
    R.u.y = c ? A.u.y : B.u.y;
    R.u.z = c ? A.u.z : B.u.z;
    R.u.w = c ? A.u.w : B.u.w;
    return R.h;
}

// ---------------- Kernel 0a: weights fp32 -> bf16 ----------------
__global__ __launch_bounds__(256) void conv_w_kernel(
    const float* __restrict__ qkv_w, const float* __restrict__ proj_w,
    const float* __restrict__ fc1_w, const float* __restrict__ fc2_w,
    unsigned short* __restrict__ ws)
{
    const int i = blockIdx.x * 256 + threadIdx.x;
    if (i < 27648)       ws[i] = f2b(qkv_w[i]);
    else if (i < 36864)  ws[i] = f2b(proj_w[i - 27648]);
    else if (i < 73728)  ws[i] = f2b(fc1_w[i - 36864]);
    else if (i < 110592) ws[i] = f2b(fc2_w[i - 73728]);
}

// ---------------- Kernel 0b: bias+mask in MFMA C-fragment layout, bf16 ----------------
__global__ __launch_bounds__(256) void build_bmfrag_kernel(
    const float* __restrict__ attn_mask, const float* __restrict__ rel_bias_table,
    const int* __restrict__ rel_index, unsigned short* __restrict__ bmf)
{
    const int i = blockIdx.x * 256 + threadIdx.x;   // 196608 total
    const int lane = i & 63;
    const int mt = (i >> 6) & 3;
    const int kt = (i >> 8) & 3;
    const int t3 = i >> 10;                          // widx*3 + h
    const int h = t3 % 3, widx = t3 / 3;
    const int q = mt * 16 + (lane & 15);
    const int kb = kt * 16 + (lane >> 4) * 4;
    float vv[4];
    #pragma unroll
    for (int rr = 0; rr < 4; ++rr) {
        const int k = kb + rr;
        float val = -1.0e30f;
        if (q < 49 && k < 49) {
            const int idx = q * 49 + k;
            val = rel_bias_table[rel_index[idx] * 3 + h] + attn_mask[widx * 2401 + idx];
        }
        vv[rr] = val;
    }
    u32x2 pw;
    pw.x = (unsigned)f2b(vv[0]) | ((unsigned)f2b(vv[1]) << 16);
    pw.y = (unsigned)f2b(vv[2]) | ((unsigned)f2b(vv[3]) << 16);
    *(u32x2*)(bmf + (size_t)i * 4) = pw;
}

// ---------------- Fused kernel: 1 wave (64 threads) per 64-token window ----------------
// LDS: xt/kss [49][104]u16 (10192 B) + xchg scratch [4][16][20]u32 (5120 B)
//      + wpre [2][12][512]u16 (24576 B) MLP weight prefetch buffers.
// Single wave -> program-order LDS, NO barriers.
__global__ __launch_bounds__(64, 2) void swin_fused(
    const float* __restrict__ x,
    const float* __restrict__ ln1_g, const float* __restrict__ ln1_b,
    const float* __restrict__ qkv_b, const float* __restrict__ proj_b,
    const float* __restrict__ ln2_g, const float* __restrict__ ln2_b,
    const float* __restrict__ fc1_b, const float* __restrict__ fc2_b,
    const unsigned short* __restrict__ wqkv,   // [288][96] bf16
    const unsigned short* __restrict__ wproj,  // [96][96] bf16
    const unsigned short* __restrict__ wfc1,   // [384][96] bf16
    const unsigned short* __restrict__ wfc2,   // [96][384] bf16
    const unsigned short* __restrict__ bmfrag,
    float* __restrict__ out)
{
    __shared__ __align__(16) unsigned short smem[49][104];
    __shared__ __align__(16) unsigned scx[4][16][20];
    __shared__ __align__(16) unsigned short wpre[2][12][512];
    unsigned short (*xt)[104]  = smem;
    unsigned short (*kss)[104] = smem;   // alias: written after all xt reads (1 wave)

    const int w = blockIdx.x, b = w >> 6, widx = w & 63;
    const int wi = widx >> 3, wj = widx & 7;
    const int lane = threadIdx.x;
    const int l15 = lane & 15, gq = lane >> 4;
    const int lk = gq * 8, g4 = gq * 4;

    #define XCHG(dst, slot, p00, p01, p10, p11)                                   \
        {                                                                          \
            unsigned* row_ = &scx[slot][l15][0];                                   \
            *(u32x2*)(row_ + gq * 2)     = (u32x2){(p00), (p01)};                  \
            *(u32x2*)(row_ + 8 + gq * 2) = (u32x2){(p10), (p11)};                  \
            (dst) = *(const bf16x8*)(row_ + gq * 4);                               \
        }

    // issue one 16x32 bf16 tile (1 KB) into wpre[buf][tidx] via global_load_lds
    #define ISSUE_TILE(bufi, tidx, srcptr)                                         \
        __builtin_amdgcn_global_load_lds(                                          \
            (const __attribute__((address_space(1))) unsigned int*)(const void*)(srcptr), \
            (__attribute__((address_space(3))) unsigned int*)(void*)&wpre[bufi][tidx][0], \
            16, 0, 0);

    // global row bases for the 4 tokens this lane owns post-attn (mt*16 + l15)
    size_t xrow[4];
    #pragma unroll
    for (int mt = 0; mt < 4; ++mt) {
        const int tok = mt * 16 + l15;
        const int p = tok / 7, qq = tok - 7 * p;
        int sr = wi * 7 + p + 3;   if (sr >= 56) sr -= 56;
        int scl = wj * 7 + qq + 3; if (scl >= 56) scl -= 56;
        xrow[mt] = ((size_t)b * 3136 + (size_t)(sr * 56 + scl)) * CDIM;
    }

    // ---- Phase 1: LN1 + shifted gather, one lane per row (49 rows), two-pass ----
    {
        const int n = lane;
        if (n < 49) {
            const int p = n / 7, qq = n - 7 * p;
            int sr = wi * 7 + p + 3;   if (sr >= 56) sr -= 56;
            int scl = wj * 7 + qq + 3; if (scl >= 56) scl -= 56;
            const float* xr = x + ((size_t)b * 3136 + (size_t)(sr * 56 + scl)) * CDIM;
            float s = 0.f, ss2 = 0.f;
            #pragma unroll
            for (int i = 0; i < 24; ++i) {
                const float4 f = *(const float4*)(xr + i * 4);
                s += f.x + f.y + f.z + f.w;
                ss2 += f.x*f.x + f.y*f.y + f.z*f.z + f.w*f.w;
            }
            const float mean = s * (1.f / 96.f);
            const float rstd = rsqrtf(ss2 * (1.f / 96.f) - mean * mean + 1e-5f);
            #pragma unroll
            for (int i = 0; i < 12; ++i) {
                const float4 f0 = *(const float4*)(xr + i * 8);
                const float4 f1 = *(const float4*)(xr + i * 8 + 4);
                const float4 g0 = *(const float4*)(ln1_g + i * 8);
                const float4 g1 = *(const float4*)(ln1_g + i * 8 + 4);
                const float4 b0 = *(const float4*)(ln1_b + i * 8);
                const float4 b1 = *(const float4*)(ln1_b + i * 8 + 4);
                u32x4 pv;
                pv.x = pkcvt((f0.x-mean)*rstd*g0.x + b0.x, (f0.y-mean)*rstd*g0.y + b0.y);
                pv.y = pkcvt((f0.z-mean)*rstd*g0.z + b0.z, (f0.w-mean)*rstd*g0.w + b0.w);
                pv.z = pkcvt((f1.x-mean)*rstd*g1.x + b1.x, (f1.y-mean)*rstd*g1.y + b1.y);
                pv.w = pkcvt((f1.z-mean)*rstd*g1.z + b1.z, (f1.w-mean)*rstd*g1.w + b1.w);
                *(u32x4*)&xt[n][i * 8] = pv;
            }
        }
    }

    // ---- Phase 2: hoist 4 token-tile B-frags (mt=3 clamped+masked); Q,V regs; K -> kss ----
    bf16x8 bx[4][3];
    #pragma unroll
    for (int mt = 0; mt < 3; ++mt)
        #pragma unroll
        for (int c = 0; c < 3; ++c)
            bx[mt][c] = *(const bf16x8*)&xt[mt * 16 + l15][c * 32 + lk];
    {
        const bool valid = (l15 == 0);               // token 48 only
        #pragma unroll
        for (int c = 0; c < 3; ++c) {
            const bf16x8 ld = *(const bf16x8*)&xt[48][c * 32 + lk];   // broadcast row 48
            const bf16x8 z = {};
            bx[3][c] = sel8(valid, ld, z);
        }
    }

    // Q swapped (scale+bias folded): weight frags loaded once, used 4x
    bf16x8 qfrag[4][3];
    #pragma unroll
    for (int c = 0; c < 3; ++c) {            // c == head
        const unsigned short* wr0 = wqkv + (size_t)((2*c) * 16 + l15) * 96;
        const unsigned short* wr1 = wqkv + (size_t)((2*c+1) * 16 + l15) * 96;
        bf16x8 wA[3], wB[3];
        #pragma unroll
        for (int i = 0; i < 3; ++i) {
            wA[i] = *(const bf16x8*)(wr0 + i * 32 + lk);
            wB[i] = *(const bf16x8*)(wr1 + i * 32 + lk);
        }
        const float4 qb0 = *(const float4*)(qkv_b + (2*c) * 16 + g4);
        const float4 qb1 = *(const float4*)(qkv_b + (2*c+1) * 16 + g4);
        #pragma unroll
        for (int mt = 0; mt < 4; ++mt) {
            f32x4 aA = {0.f,0.f,0.f,0.f}, aB = {0.f,0.f,0.f,0.f};
            #pragma unroll
            for (int i = 0; i < 3; ++i) {
                aA = __builtin_amdgcn_mfma_f32_16x16x32_bf16(wA[i], bx[mt][i], aA, 0, 0, 0);
                aB = __builtin_amdgcn_mfma_f32_16x16x32_bf16(wB[i], bx[mt][i], aB, 0, 0, 0);
            }
            const unsigned pk00 = pkcvt((aA[0] + qb0.x) * SCALE_QK, (aA[1] + qb0.y) * SCALE_QK);
            const unsigned pk01 = pkcvt((aA[2] + qb0.z) * SCALE_QK, (aA[3] + qb0.w) * SCALE_QK);
            const unsigned pk10 = pkcvt((aB[0] + qb1.x) * SCALE_QK, (aB[1] + qb1.y) * SCALE_QK);
            const unsigned pk11 = pkcvt((aB[2] + qb1.z) * SCALE_QK, (aB[3] + qb1.w) * SCALE_QK);
            XCHG(qfrag[mt][c], mt, pk00, pk01, pk10, pk11);
        }
    }

    // V normal GEMM -> xchg over token-tile pairs: vfrag[vf][tc] = [vfeat l15][tok lk]
    bf16x8 vfrag[6][2];
    #pragma unroll
    for (int vf = 0; vf < 6; ++vf) {
        const unsigned short* wr = wqkv + (size_t)(192 + vf * 16 + l15) * 96;
        bf16x8 wV[3];
        #pragma unroll
        for (int i = 0; i < 3; ++i) wV[i] = *(const bf16x8*)(wr + i * 32 + lk);
        const float bias = qkv_b[192 + vf * 16 + l15];
        f32x4 a[4];
        #pragma unroll
        for (int mt = 0; mt < 4; ++mt) {
            f32x4 acc = {0.f,0.f,0.f,0.f};
            #pragma unroll
            for (int i = 0; i < 3; ++i)
                acc = __builtin_amdgcn_mfma_f32_16x16x32_bf16(bx[mt][i], wV[i], acc, 0, 0, 0);
            a[mt] = acc;
        }
        #pragma unroll
        for (int tc = 0; tc < 2; ++tc) {
            const unsigned pk00 = pkcvt(a[2*tc][0] + bias, a[2*tc][1] + bias);
            const unsigned pk01 = pkcvt(a[2*tc][2] + bias, a[2*tc][3] + bias);
            const unsigned pk10 = pkcvt(a[2*tc+1][0] + bias, a[2*tc+1][1] + bias);
            const unsigned pk11 = pkcvt(a[2*tc+1][2] + bias, a[2*tc+1][3] + bias);
            XCHG(vfrag[vf][tc], ((vf * 2 + tc) & 3), pk00, pk01, pk10, pk11);
        }
    }

    // K swapped -> kss rows < 49 (RUNTIME loop)
    #pragma unroll 1
    for (int t = 0; t < 6; ++t) {
        const unsigned short* wr = wqkv + (size_t)((6 + t) * 16 + l15) * 96;
        bf16x8 wK[3];
        #pragma unroll
        for (int i = 0; i < 3; ++i) wK[i] = *(const bf16x8*)(wr + i * 32 + lk);
        const float4 kb4 = *(const float4*)(qkv_b + (6 + t) * 16 + g4);
        #pragma unroll
        for (int mt = 0; mt < 4; ++mt) {
            f32x4 acc = {0.f,0.f,0.f,0.f};
            #pragma unroll
            for (int i = 0; i < 3; ++i)
                acc = __builtin_amdgcn_mfma_f32_16x16x32_bf16(wK[i], bx[mt][i], acc, 0, 0, 0);
            const int tok = mt * 16 + l15;
            if (tok < 49) {
                u32x2 pw;
                pw.x = pkcvt(acc[0] + kb4.x, acc[1] + kb4.y);
                pw.y = pkcvt(acc[2] + kb4.z, acc[3] + kb4.w);
                *(u32x2*)&kss[tok][t * 16 + g4] = pw;
            }
        }
    }

    // ---- Phase 3: per head: QK^T (swapped) + register softmax + PV -> bxA ----
    bf16x8 bxA[4][3];
    #pragma unroll
    for (int h = 0; h < 3; ++h) {
        bf16x8 kb8;
        {
            const float4 kb0 = *(const float4*)(qkv_b + 96 + h * 32 + lk);
            const float4 kb1 = *(const float4*)(qkv_b + 96 + h * 32 + lk + 4);
            kb8 = mk8(pkcvt(kb0.x, kb0.y), pkcvt(kb0.z, kb0.w),
                      pkcvt(kb1.x, kb1.y), pkcvt(kb1.z, kb1.w));
        }
        bf16x8 ak[4];
        #pragma unroll
        for (int kt = 0; kt < 3; ++kt)
            ak[kt] = *(const bf16x8*)&kss[kt * 16 + l15][h * 32 + lk];
        {
            const bf16x8 ld48 = *(const bf16x8*)&kss[48][h * 32 + lk];  // broadcast
            ak[3] = sel8(l15 == 0, ld48, kb8);
        }
        #pragma unroll
        for (int mt = 0; mt < 4; ++mt) {
            const unsigned short* bmb = bmfrag + (size_t)(widx * 3 + h) * 4096 + mt * 256;
            f32x4 s[4];
            #pragma unroll
            for (int kt = 0; kt < 4; ++kt) {
                const u32x2 cw = *(const u32x2*)(bmb + kt * 1024 + lane * 4);
                f32x4 c;
                c[0] = bitsf(cw.x << 16); c[1] = bitsf(cw.x & 0xffff0000u);
                c[2] = bitsf(cw.y << 16); c[3] = bitsf(cw.y & 0xffff0000u);
                s[kt] = __builtin_amdgcn_mfma_f32_16x16x32_bf16(ak[kt], qfrag[mt][h], c, 0, 0, 0);
            }
            float mx = s[0][0];
            #pragma unroll
            for (int kt = 0; kt < 4; ++kt)
                #pragma unroll
                for (int rr = 0; rr < 4; ++rr) mx = fmaxf(mx, s[kt][rr]);
            mx = fmaxf(mx, __shfl_xor(mx, 16));
            mx = fmaxf(mx, __shfl_xor(mx, 32));
            float sum = 0.f;
            #pragma unroll
            for (int kt = 0; kt < 4; ++kt)
                #pragma unroll
                for (int rr = 0; rr < 4; ++rr) {
                    const float e = __expf(s[kt][rr] - mx);
                    s[kt][rr] = e; sum += e;
                }
            sum += __shfl_xor(sum, 16);
            sum += __shfl_xor(sum, 32);
            const float inv = __fdividef(1.0f, sum);
            const unsigned pk00 = pkcvt(s[0][0], s[0][1]), pk01 = pkcvt(s[0][2], s[0][3]);
            const unsigned pk10 = pkcvt(s[1][0], s[1][1]), pk11 = pkcvt(s[1][2], s[1][3]);
            const unsigned pk20 = pkcvt(s[2][0], s[2][1]), pk21 = pkcvt(s[2][2], s[2][3]);
            const unsigned pk30 = pkcvt(s[3][0], s[3][1]), pk31 = pkcvt(s[3][2], s[3][3]);
            bf16x8 pb0, pb1;
            XCHG(pb0, 0, pk00, pk01, pk10, pk11);
            XCHG(pb1, 1, pk20, pk21, pk30, pk31);
            f32x4 o0 = {0.f,0.f,0.f,0.f}, o1 = {0.f,0.f,0.f,0.f};
            o0 = __builtin_amdgcn_mfma_f32_16x16x32_bf16(vfrag[h*2][0],   pb0, o0, 0, 0, 0);
            o0 = __builtin_amdgcn_mfma_f32_16x16x32_bf16(vfrag[h*2][1],   pb1, o0, 0, 0, 0);
            o1 = __builtin_amdgcn_mfma_f32_16x16x32_bf16(vfrag[h*2+1][0], pb0, o1, 0, 0, 0);
            o1 = __builtin_amdgcn_mfma_f32_16x16x32_bf16(vfrag[h*2+1][1], pb1, o1, 0, 0, 0);
            const unsigned q00 = pkcvt(o0[0] * inv, o0[1] * inv);
            const unsigned q01 = pkcvt(o0[2] * inv, o0[3] * inv);
            const unsigned q10 = pkcvt(o1[0] * inv, o1[1] * inv);
            const unsigned q11 = pkcvt(o1[2] * inv, o1[3] * inv);
            XCHG(bxA[mt][h], 2, q00, q01, q10, q11);
        }
    }

    // ---- Phase 4: proj (swapped) + bias + residual -> hacc[mt][ct] ----
    f32x4 hacc[4][6];
    #pragma unroll
    for (int ct = 0; ct < 6; ++ct) {
        const unsigned short* wr = wproj + (size_t)(ct * 16 + l15) * 96;
        bf16x8 wp[3];
        #pragma unroll
        for (int i = 0; i < 3; ++i) wp[i] = *(const bf16x8*)(wr + i * 32 + lk);
        const float4 pb4 = *(const float4*)(proj_b + ct * 16 + g4);
        #pragma unroll
        for (int mt = 0; mt < 4; ++mt) {
            f32x4 acc = {0.f,0.f,0.f,0.f};
            #pragma unroll
            for (int i = 0; i < 3; ++i)
                acc = __builtin_amdgcn_mfma_f32_16x16x32_bf16(wp[i], bxA[mt][i], acc, 0, 0, 0);
            const float4 xv = *(const float4*)(x + xrow[mt] + ct * 16 + g4);
            hacc[mt][ct][0] = acc[0] + pb4.x + xv.x;
            hacc[mt][ct][1] = acc[1] + pb4.y + xv.y;
            hacc[mt][ct][2] = acc[2] + pb4.z + xv.z;
            hacc[mt][ct][3] = acc[3] + pb4.w + xv.w;
        }
    }

    // ---- Phase 5: LN2 in-register per mt -> mbx[mt][kc]; fold fc2 bias into hacc ----
    bf16x8 mbx[4][3];
    #pragma unroll
    for (int mt = 0; mt < 4; ++mt) {
        float s = 0.f, ss2 = 0.f;
        #pragma unroll
        for (int ct = 0; ct < 6; ++ct)
            #pragma unroll
            for (int rr = 0; rr < 4; ++rr) { s += hacc[mt][ct][rr]; ss2 += hacc[mt][ct][rr] * hacc[mt][ct][rr]; }
        s += __shfl_xor(s, 16);  ss2 += __shfl_xor(ss2, 16);
        s += __shfl_xor(s, 32);  ss2 += __shfl_xor(ss2, 32);
        const float mean = s * (1.f / 96.f);
        const float rstd = rsqrtf(ss2 * (1.f / 96.f) - mean * mean + 1e-5f);
        #pragma unroll
        for (int kc = 0; kc < 3; ++kc) {
            const float4 g0 = *(const float4*)(ln2_g + (2*kc) * 16 + g4);
            const float4 b0 = *(const float4*)(ln2_b + (2*kc) * 16 + g4);
            const float4 g1 = *(const float4*)(ln2_g + (2*kc+1) * 16 + g4);
            const float4 b1 = *(const float4*)(ln2_b + (2*kc+1) * 16 + g4);
            const float* g0p = &g0.x; const float* b0p = &b0.x;
            const float* g1p = &g1.x; const float* b1p = &b1.x;
            float v0[4], v1[4];
            #pragma unroll
            for (int rr = 0; rr < 4; ++rr) {
                v0[rr] = (hacc[mt][2*kc][rr]   - mean) * rstd * g0p[rr] + b0p[rr];
                v1[rr] = (hacc[mt][2*kc+1][rr] - mean) * rstd * g1p[rr] + b1p[rr];
            }
            const unsigned pk00 = pkcvt(v0[0], v0[1]), pk01 = pkcvt(v0[2], v0[3]);
            const unsigned pk10 = pkcvt(v1[0], v1[1]), pk11 = pkcvt(v1[2], v1[3]);
            XCHG(mbx[mt][kc], kc, pk00, pk01, pk10, pk11);
        }
    }
    #pragma unroll
    for (int ct = 0; ct < 6; ++ct) {
        const float4 b2v = *(const float4*)(fc2_b + ct * 16 + g4);
        #pragma unroll
        for (int mt = 0; mt < 4; ++mt) {
            hacc[mt][ct][0] += b2v.x; hacc[mt][ct][1] += b2v.y;
            hacc[mt][ct][2] += b2v.z; hacc[mt][ct][3] += b2v.w;
        }
    }

    // ---- Phase 6: MLP with double-buffered global_load_lds weight prefetch ----
    // chunk tiles: 0..2 = fc1 rows[hb..hb+15] colgrp i; 3..5 = fc1 rows[hb+16..+31];
    //              6..11 = fc2 rows[ct*16..] cols[hb..hb+31].
    // prologue: issue chunk 0 into buf 0
    {
        const int hb0 = 0;
        #pragma unroll
        for (int i = 0; i < 3; ++i) {
            ISSUE_TILE(0, i,     wfc1 + (size_t)(hb0 + l15) * 96 + i * 32 + lk);
            ISSUE_TILE(0, 3 + i, wfc1 + (size_t)(hb0 + 16 + l15) * 96 + i * 32 + lk);
        }
        #pragma unroll
        for (int ct = 0; ct < 6; ++ct)
            ISSUE_TILE(0, 6 + ct, wfc2 + (size_t)(ct * 16 + l15) * 384 + hb0 + lk);
    }
    #pragma unroll 1
    for (int kc = 0; kc < 12; ++kc) {
        const int buf = kc & 1;
        const int hb = kc * 32;
        // bias loads for this chunk (2 vm ops)
        const float4 bv0 = *(const float4*)(fc1_b + hb + g4);
        const float4 bv1 = *(const float4*)(fc1_b + hb + 16 + g4);
        // issue next chunk (12 vm ops)
        if (kc < 11) {
            const int hb1 = hb + 32, nb = buf ^ 1;
            #pragma unroll
            for (int i = 0; i < 3; ++i) {
                ISSUE_TILE(nb, i,     wfc1 + (size_t)(hb1 + l15) * 96 + i * 32 + lk);
                ISSUE_TILE(nb, 3 + i, wfc1 + (size_t)(hb1 + 16 + l15) * 96 + i * 32 + lk);
            }
            #pragma unroll
            for (int ct = 0; ct < 6; ++ct)
                ISSUE_TILE(nb, 6 + ct, wfc2 + (size_t)(ct * 16 + l15) * 384 + hb1 + lk);
            asm volatile("s_waitcnt vmcnt(14)" ::: "memory");   // chunk kc tiles done
        } else {
            asm volatile("s_waitcnt vmcnt(2)" ::: "memory");    // only 2 bias loads newer
        }
        __builtin_amdgcn_sched_barrier(0);
        // fragments from LDS (each lane reads its own 16B slot)
        bf16x8 w0f[3], w1f[3];
        #pragma unroll
        for (int i = 0; i < 3; ++i) {
            w0f[i] = *(const bf16x8*)&wpre[buf][i][lane * 8];
            w1f[i] = *(const bf16x8*)&wpre[buf][3 + i][lane * 8];
        }
        const float* b0p = &bv0.x; const float* b1p = &bv1.x;
        bf16x8 pb[4];
        #pragma unroll
        for (int mt = 0; mt < 4; ++mt) {
            f32x4 s0 = {0.f,0.f,0.f,0.f}, s1 = {0.f,0.f,0.f,0.f};
            #pragma unroll
            for (int i = 0; i < 3; ++i) {
                s0 = __builtin_amdgcn_mfma_f32_16x16x32_bf16(w0f[i], mbx[mt][i], s0, 0, 0, 0);
                s1 = __builtin_amdgcn_mfma_f32_16x16x32_bf16(w1f[i], mbx[mt][i], s1, 0, 0, 0);
            }
            float ge0[4], ge1[4];
            #pragma unroll
            for (int rr = 0; rr < 4; ++rr) {
                float u = s0[rr] + b0p[rr];
                float u2 = u * u;
                float n2y = u * (-1.5957691216f - 0.0713548162f * u2);
                ge0[rr] = __fdividef(u, 1.f + __expf(n2y));
                u = s1[rr] + b1p[rr];
                u2 = u * u;
                n2y = u * (-1.5957691216f - 0.0713548162f * u2);
                ge1[rr] = __fdividef(u, 1.f + __expf(n2y));
            }
            const unsigned pk00 = pkcvt(ge0[0], ge0[1]), pk01 = pkcvt(ge0[2], ge0[3]);
            const unsigned pk10 = pkcvt(ge1[0], ge1[1]), pk11 = pkcvt(ge1[2], ge1[3]);
            XCHG(pb[mt], mt, pk00, pk01, pk10, pk11);
        }
        #pragma unroll
        for (int ct = 0; ct < 6; ++ct) {
            const bf16x8 w2f = *(const bf16x8*)&wpre[buf][6 + ct][lane * 8];
            #pragma unroll
            for (int mt = 0; mt < 4; ++mt)
                hacc[mt][ct] = __builtin_amdgcn_mfma_f32_16x16x32_bf16(w2f, pb[mt], hacc[mt][ct], 0, 0, 0);
        }
    }

    // ---- Phase 7: coalesced float4 stores, 4 owned token rows ----
    #pragma unroll
    for (int mt = 0; mt < 4; ++mt) {
        const int tok = mt * 16 + l15;
        if (tok < 49) {
            float* ob = out + xrow[mt];
            #pragma unroll
            for (int ct = 0; ct < 6; ++ct) {
                float4 o4;
                o4.x = hacc[mt][ct][0]; o4.y = hacc[mt][ct][1];
                o4.z = hacc[mt][ct][2]; o4.w = hacc[mt][ct][3];
                *(float4*)(ob + ct * 16 + g4) = o4;
            }
        }
    }
    #undef XCHG
    #undef ISSUE_TILE
}

extern "C" void kernel_launch(void* const* d_in, const int* in_sizes, int n_in,
                              void* d_out, int out_size, void* d_ws, size_t ws_size,
                              hipStream_t stream) {
    (void)n_in; (void)out_size; (void)ws_size;
    const float* x        = (const float*)d_in[0];
    const float* attn_msk = (const float*)d_in[1];
    const float* ln1_g    = (const float*)d_in[2];
    const float* ln1_b    = (const float*)d_in[3];
    const float* qkv_w    = (const float*)d_in[4];
    const float* qkv_b    = (const float*)d_in[5];
    const float* rel_tab  = (const float*)d_in[6];
    const int*   rel_idx  = (const int*)d_in[7];
    const float* proj_w   = (const float*)d_in[8];
    const float* proj_b   = (const float*)d_in[9];
    const float* ln2_g    = (const float*)d_in[10];
    const float* ln2_b    = (const float*)d_in[11];
    const float* fc1_w    = (const float*)d_in[12];
    const float* fc1_b    = (const float*)d_in[13];
    const float* fc2_w    = (const float*)d_in[14];
    const float* fc2_b    = (const float*)d_in[15];
    float* out = (float*)d_out;
    unsigned short* wsb = (unsigned short*)d_ws;
    unsigned short* bmf = wsb + 110592;

    const int B = in_sizes[0] / (3136 * 96);   // 64

    conv_w_kernel<<<(110592 + 255) / 256, 256, 0, stream>>>(qkv_w, proj_w, fc1_w, fc2_w, wsb);
    build_bmfrag_kernel<<<196608 / 256, 256, 0, stream>>>(attn_msk, rel_tab, rel_idx, bmf);

    swin_fused<<<B * 64, 64, 0, stream>>>(
        x, ln1_g, ln1_b, qkv_b, proj_b, ln2_g, ln2_b, fc1_b, fc2_b,
        wsb, wsb + 27648, wsb + 36864, wsb + 73728, bmf, out);
}

// Round 20
// 183.434 us; speedup vs baseline: 1.2552x; 1.2552x over previous
//
#include <hip/hip_runtime.h>
#include <math.h>

// Swin block R20: strict revert to R18 (best measured: 203us kernel / 187us wall).
// R19's global_load_lds prefetch raised VGPR 128->180, halving occupancy -> regression.
// 1 wave/window, 4 token-tiles register-blocked, LDS-scratch xchg, zero barriers.
// B=64, H=W=56, C=96, WS=7, SS=3, NH=3, HD=32, N=49 (padded 64), nW=64.

#define CDIM 96
#define SCALE_QK 0.17677669529663687f  // 32^-0.5

typedef __attribute__((ext_vector_type(8))) short bf16x8;
typedef __attribute__((ext_vector_type(4))) float f32x4;
typedef __attribute__((ext_vector_type(2))) unsigned int u32x2;
typedef __attribute__((ext_vector_type(4))) unsigned int u32x4;

__device__ inline unsigned short f2b(float f) {
    union { float f; unsigned u; } v; v.f = f;
    unsigned r = v.u + 0x7FFF + ((v.u >> 16) & 1);   // RNE
    return (unsigned short)(r >> 16);
}
__device__ inline unsigned pkcvt(float a, float b) {   // low16=bf16(a), high16=bf16(b)
    unsigned d;
    asm("v_cvt_pk_bf16_f32 %0, %1, %2" : "=v"(d) : "v"(a), "v"(b));
    return d;
}
__device__ inline float bitsf(unsigned u) {
    union { unsigned u; float f; } v; v.u = u; return v.f;
}
__device__ inline bf16x8 mk8(unsigned d0, unsigned d1, unsigned d2, unsigned d3) {
    union { u32x4 u; bf16x8 h; } v;
    v.u = (u32x4){d0, d1, d2, d3};
    return v.h;
}
__device__ inline bf16x8 sel8(bool c, bf16x8 a, bf16x8 b) {   // c ? a : b per dword
    union { bf16x8 h; u32x4 u; } A, B, R;
    A.h = a; B.h = b;
    R.u.x = c ? A.u.x : B.u.x;
    R.u.y = c ? A.u.y : B.u.y;
    R.u.z = c ? A.u.z : B.u.z;
    R.u.w = c ? A.u.w : B.u.w;
    return R.h;
}

// ---------------- Kernel 0a: weights fp32 -> bf16 ----------------
__global__ __launch_bounds__(256) void conv_w_kernel(
    const float* __restrict__ qkv_w, const float* __restrict__ proj_w,
    const float* __restrict__ fc1_w, const float* __restrict__ fc2_w,
    unsigned short* __restrict__ ws)
{
    const int i = blockIdx.x * 256 + threadIdx.x;
    if (i < 27648)       ws[i] = f2b(qkv_w[i]);
    else if (i < 36864)  ws[i] = f2b(proj_w[i - 27648]);
    else if (i < 73728)  ws[i] = f2b(fc1_w[i - 36864]);
    else if (i < 110592) ws[i] = f2b(fc2_w[i - 73728]);
}

// ---------------- Kernel 0b: bias+mask in MFMA C-fragment layout, bf16 ----------------
__global__ __launch_bounds__(256) void build_bmfrag_kernel(
    const float* __restrict__ attn_mask, const float* __restrict__ rel_bias_table,
    const int* __restrict__ rel_index, unsigned short* __restrict__ bmf)
{
    const int i = blockIdx.x * 256 + threadIdx.x;   // 196608 total
    const int lane = i & 63;
    const int mt = (i >> 6) & 3;
    const int kt = (i >> 8) & 3;
    const int t3 = i >> 10;                          // widx*3 + h
    const int h = t3 % 3, widx = t3 / 3;
    const int q = mt * 16 + (lane & 15);
    const int kb = kt * 16 + (lane >> 4) * 4;
    float vv[4];
    #pragma unroll
    for (int rr = 0; rr < 4; ++rr) {
        const int k = kb + rr;
        float val = -1.0e30f;
        if (q < 49 && k < 49) {
            const int idx = q * 49 + k;
            val = rel_bias_table[rel_index[idx] * 3 + h] + attn_mask[widx * 2401 + idx];
        }
        vv[rr] = val;
    }
    u32x2 pw;
    pw.x = (unsigned)f2b(vv[0]) | ((unsigned)f2b(vv[1]) << 16);
    pw.y = (unsigned)f2b(vv[2]) | ((unsigned)f2b(vv[3]) << 16);
    *(u32x2*)(bmf + (size_t)i * 4) = pw;
}

// ---------------- Fused kernel: 1 wave (64 threads) per 64-token window ----------------
// LDS: xt/kss [49][104]u16 (10192 B) + xchg scratch [4][16][20]u32 (5120 B).
// Single wave -> program-order LDS, NO barriers.
__global__ __launch_bounds__(64, 2) void swin_fused(
    const float* __restrict__ x,
    const float* __restrict__ ln1_g, const float* __restrict__ ln1_b,
    const float* __restrict__ qkv_b, const float* __restrict__ proj_b,
    const float* __restrict__ ln2_g, const float* __restrict__ ln2_b,
    const float* __restrict__ fc1_b, const float* __restrict__ fc2_b,
    const unsigned short* __restrict__ wqkv,   // [288][96] bf16
    const unsigned short* __restrict__ wproj,  // [96][96] bf16
    const unsigned short* __restrict__ wfc1,   // [384][96] bf16
    const unsigned short* __restrict__ wfc2,   // [96][384] bf16
    const unsigned short* __restrict__ bmfrag,
    float* __restrict__ out)
{
    __shared__ __align__(16) unsigned short smem[49][104];
    __shared__ __align__(16) unsigned scx[4][16][20];
    unsigned short (*xt)[104]  = smem;
    unsigned short (*kss)[104] = smem;   // alias: written after all xt reads (1 wave)

    const int w = blockIdx.x, b = w >> 6, widx = w & 63;
    const int wi = widx >> 3, wj = widx & 7;
    const int lane = threadIdx.x;
    const int l15 = lane & 15, gq = lane >> 4;
    const int lk = gq * 8, g4 = gq * 4;

    // LDS-scratch exchange: C-frag (2 tiles of swapped GEMM) -> B/A-frag.
    #define XCHG(dst, slot, p00, p01, p10, p11)                                   \
        {                                                                          \
            unsigned* row_ = &scx[slot][l15][0];                                   \
            *(u32x2*)(row_ + gq * 2)     = (u32x2){(p00), (p01)};                  \
            *(u32x2*)(row_ + 8 + gq * 2) = (u32x2){(p10), (p11)};                  \
            (dst) = *(const bf16x8*)(row_ + gq * 4);                               \
        }

    // global row bases for the 4 tokens this lane owns post-attn (mt*16 + l15)
    size_t xrow[4];
    #pragma unroll
    for (int mt = 0; mt < 4; ++mt) {
        const int tok = mt * 16 + l15;
        const int p = tok / 7, qq = tok - 7 * p;
        int sr = wi * 7 + p + 3;   if (sr >= 56) sr -= 56;
        int scl = wj * 7 + qq + 3; if (scl >= 56) scl -= 56;
        xrow[mt] = ((size_t)b * 3136 + (size_t)(sr * 56 + scl)) * CDIM;
    }

    // ---- Phase 1: LN1 + shifted gather, one lane per row (49 rows), two-pass ----
    {
        const int n = lane;
        if (n < 49) {
            const int p = n / 7, qq = n - 7 * p;
            int sr = wi * 7 + p + 3;   if (sr >= 56) sr -= 56;
            int scl = wj * 7 + qq + 3; if (scl >= 56) scl -= 56;
            const float* xr = x + ((size_t)b * 3136 + (size_t)(sr * 56 + scl)) * CDIM;
            float s = 0.f, ss2 = 0.f;
            #pragma unroll
            for (int i = 0; i < 24; ++i) {
                const float4 f = *(const float4*)(xr + i * 4);
                s += f.x + f.y + f.z + f.w;
                ss2 += f.x*f.x + f.y*f.y + f.z*f.z + f.w*f.w;
            }
            const float mean = s * (1.f / 96.f);
            const float rstd = rsqrtf(ss2 * (1.f / 96.f) - mean * mean + 1e-5f);
            #pragma unroll
            for (int i = 0; i < 12; ++i) {
                const float4 f0 = *(const float4*)(xr + i * 8);
                const float4 f1 = *(const float4*)(xr + i * 8 + 4);
                const float4 g0 = *(const float4*)(ln1_g + i * 8);
                const float4 g1 = *(const float4*)(ln1_g + i * 8 + 4);
                const float4 b0 = *(const float4*)(ln1_b + i * 8);
                const float4 b1 = *(const float4*)(ln1_b + i * 8 + 4);
                u32x4 pv;
                pv.x = pkcvt((f0.x-mean)*rstd*g0.x + b0.x, (f0.y-mean)*rstd*g0.y + b0.y);
                pv.y = pkcvt((f0.z-mean)*rstd*g0.z + b0.z, (f0.w-mean)*rstd*g0.w + b0.w);
                pv.z = pkcvt((f1.x-mean)*rstd*g1.x + b1.x, (f1.y-mean)*rstd*g1.y + b1.y);
                pv.w = pkcvt((f1.z-mean)*rstd*g1.z + b1.z, (f1.w-mean)*rstd*g1.w + b1.w);
                *(u32x4*)&xt[n][i * 8] = pv;
            }
        }
    }

    // ---- Phase 2: hoist 4 token-tile B-frags (mt=3 clamped+masked); Q,V regs; K -> kss ----
    bf16x8 bx[4][3];
    #pragma unroll
    for (int mt = 0; mt < 3; ++mt)
        #pragma unroll
        for (int c = 0; c < 3; ++c)
            bx[mt][c] = *(const bf16x8*)&xt[mt * 16 + l15][c * 32 + lk];
    {
        const bool valid = (l15 == 0);               // token 48 only
        #pragma unroll
        for (int c = 0; c < 3; ++c) {
            const bf16x8 ld = *(const bf16x8*)&xt[48][c * 32 + lk];   // broadcast row 48
            const bf16x8 z = {};
            bx[3][c] = sel8(valid, ld, z);
        }
    }

    // Q swapped (scale+bias folded): weight frags loaded once, used 4x
    bf16x8 qfrag[4][3];
    #pragma unroll
    for (int c = 0; c < 3; ++c) {            // c == head
        const unsigned short* wr0 = wqkv + (size_t)((2*c) * 16 + l15) * 96;
        const unsigned short* wr1 = wqkv + (size_t)((2*c+1) * 16 + l15) * 96;
        bf16x8 wA[3], wB[3];
        #pragma unroll
        for (int i = 0; i < 3; ++i) {
            wA[i] = *(const bf16x8*)(wr0 + i * 32 + lk);
            wB[i] = *(const bf16x8*)(wr1 + i * 32 + lk);
        }
        const float4 qb0 = *(const float4*)(qkv_b + (2*c) * 16 + g4);
        const float4 qb1 = *(const float4*)(qkv_b + (2*c+1) * 16 + g4);
        #pragma unroll
        for (int mt = 0; mt < 4; ++mt) {
            f32x4 aA = {0.f,0.f,0.f,0.f}, aB = {0.f,0.f,0.f,0.f};
            #pragma unroll
            for (int i = 0; i < 3; ++i) {
                aA = __builtin_amdgcn_mfma_f32_16x16x32_bf16(wA[i], bx[mt][i], aA, 0, 0, 0);
                aB = __builtin_amdgcn_mfma_f32_16x16x32_bf16(wB[i], bx[mt][i], aB, 0, 0, 0);
            }
            const unsigned pk00 = pkcvt((aA[0] + qb0.x) * SCALE_QK, (aA[1] + qb0.y) * SCALE_QK);
            const unsigned pk01 = pkcvt((aA[2] + qb0.z) * SCALE_QK, (aA[3] + qb0.w) * SCALE_QK);
            const unsigned pk10 = pkcvt((aB[0] + qb1.x) * SCALE_QK, (aB[1] + qb1.y) * SCALE_QK);
            const unsigned pk11 = pkcvt((aB[2] + qb1.z) * SCALE_QK, (aB[3] + qb1.w) * SCALE_QK);
            XCHG(qfrag[mt][c], mt, pk00, pk01, pk10, pk11);
        }
    }

    // V normal GEMM -> xchg over token-tile pairs: vfrag[vf][tc] = [vfeat l15][tok lk]
    bf16x8 vfrag[6][2];
    #pragma unroll
    for (int vf = 0; vf < 6; ++vf) {
        const unsigned short* wr = wqkv + (size_t)(192 + vf * 16 + l15) * 96;
        bf16x8 wV[3];
        #pragma unroll
        for (int i = 0; i < 3; ++i) wV[i] = *(const bf16x8*)(wr + i * 32 + lk);
        const float bias = qkv_b[192 + vf * 16 + l15];
        f32x4 a[4];
        #pragma unroll
        for (int mt = 0; mt < 4; ++mt) {
            f32x4 acc = {0.f,0.f,0.f,0.f};
            #pragma unroll
            for (int i = 0; i < 3; ++i)
                acc = __builtin_amdgcn_mfma_f32_16x16x32_bf16(bx[mt][i], wV[i], acc, 0, 0, 0);
            a[mt] = acc;
        }
        #pragma unroll
        for (int tc = 0; tc < 2; ++tc) {
            const unsigned pk00 = pkcvt(a[2*tc][0] + bias, a[2*tc][1] + bias);
            const unsigned pk01 = pkcvt(a[2*tc][2] + bias, a[2*tc][3] + bias);
            const unsigned pk10 = pkcvt(a[2*tc+1][0] + bias, a[2*tc+1][1] + bias);
            const unsigned pk11 = pkcvt(a[2*tc+1][2] + bias, a[2*tc+1][3] + bias);
            XCHG(vfrag[vf][tc], ((vf * 2 + tc) & 3), pk00, pk01, pk10, pk11);
        }
    }

    // K swapped -> kss rows < 49 (RUNTIME loop)
    #pragma unroll 1
    for (int t = 0; t < 6; ++t) {
        const unsigned short* wr = wqkv + (size_t)((6 + t) * 16 + l15) * 96;
        bf16x8 wK[3];
        #pragma unroll
        for (int i = 0; i < 3; ++i) wK[i] = *(const bf16x8*)(wr + i * 32 + lk);
        const float4 kb4 = *(const float4*)(qkv_b + (6 + t) * 16 + g4);
        #pragma unroll
        for (int mt = 0; mt < 4; ++mt) {
            f32x4 acc = {0.f,0.f,0.f,0.f};
            #pragma unroll
            for (int i = 0; i < 3; ++i)
                acc = __builtin_amdgcn_mfma_f32_16x16x32_bf16(wK[i], bx[mt][i], acc, 0, 0, 0);
            const int tok = mt * 16 + l15;
            if (tok < 49) {
                u32x2 pw;
                pw.x = pkcvt(acc[0] + kb4.x, acc[1] + kb4.y);
                pw.y = pkcvt(acc[2] + kb4.z, acc[3] + kb4.w);
                *(u32x2*)&kss[tok][t * 16 + g4] = pw;
            }
        }
    }

    // ---- Phase 3: per head: QK^T (swapped) + register softmax + PV -> bxA ----
    bf16x8 bxA[4][3];
    #pragma unroll
    for (int h = 0; h < 3; ++h) {
        bf16x8 kb8;
        {
            const float4 kb0 = *(const float4*)(qkv_b + 96 + h * 32 + lk);
            const float4 kb1 = *(const float4*)(qkv_b + 96 + h * 32 + lk + 4);
            kb8 = mk8(pkcvt(kb0.x, kb0.y), pkcvt(kb0.z, kb0.w),
                      pkcvt(kb1.x, kb1.y), pkcvt(kb1.z, kb1.w));
        }
        bf16x8 ak[4];
        #pragma unroll
        for (int kt = 0; kt < 3; ++kt)
            ak[kt] = *(const bf16x8*)&kss[kt * 16 + l15][h * 32 + lk];
        {
            const bf16x8 ld48 = *(const bf16x8*)&kss[48][h * 32 + lk];  // broadcast
            ak[3] = sel8(l15 == 0, ld48, kb8);
        }
        #pragma unroll
        for (int mt = 0; mt < 4; ++mt) {
            const unsigned short* bmb = bmfrag + (size_t)(widx * 3 + h) * 4096 + mt * 256;
            f32x4 s[4];
            #pragma unroll
            for (int kt = 0; kt < 4; ++kt) {
                const u32x2 cw = *(const u32x2*)(bmb + kt * 1024 + lane * 4);
                f32x4 c;
                c[0] = bitsf(cw.x << 16); c[1] = bitsf(cw.x & 0xffff0000u);
                c[2] = bitsf(cw.y << 16); c[3] = bitsf(cw.y & 0xffff0000u);
                s[kt] = __builtin_amdgcn_mfma_f32_16x16x32_bf16(ak[kt], qfrag[mt][h], c, 0, 0, 0);
            }
            float mx = s[0][0];
            #pragma unroll
            for (int kt = 0; kt < 4; ++kt)
                #pragma unroll
                for (int rr = 0; rr < 4; ++rr) mx = fmaxf(mx, s[kt][rr]);
            mx = fmaxf(mx, __shfl_xor(mx, 16));
            mx = fmaxf(mx, __shfl_xor(mx, 32));
            float sum = 0.f;
            #pragma unroll
            for (int kt = 0; kt < 4; ++kt)
                #pragma unroll
                for (int rr = 0; rr < 4; ++rr) {
                    const float e = __expf(s[kt][rr] - mx);
                    s[kt][rr] = e; sum += e;
                }
            sum += __shfl_xor(sum, 16);
            sum += __shfl_xor(sum, 32);
            const float inv = __fdividef(1.0f, sum);
            const unsigned pk00 = pkcvt(s[0][0], s[0][1]), pk01 = pkcvt(s[0][2], s[0][3]);
            const unsigned pk10 = pkcvt(s[1][0], s[1][1]), pk11 = pkcvt(s[1][2], s[1][3]);
            const unsigned pk20 = pkcvt(s[2][0], s[2][1]), pk21 = pkcvt(s[2][2], s[2][3]);
            const unsigned pk30 = pkcvt(s[3][0], s[3][1]), pk31 = pkcvt(s[3][2], s[3][3]);
            bf16x8 pb0, pb1;
            XCHG(pb0, 0, pk00, pk01, pk10, pk11);
            XCHG(pb1, 1, pk20, pk21, pk30, pk31);
            f32x4 o0 = {0.f,0.f,0.f,0.f}, o1 = {0.f,0.f,0.f,0.f};
            o0 = __builtin_amdgcn_mfma_f32_16x16x32_bf16(vfrag[h*2][0],   pb0, o0, 0, 0, 0);
            o0 = __builtin_amdgcn_mfma_f32_16x16x32_bf16(vfrag[h*2][1],   pb1, o0, 0, 0, 0);
            o1 = __builtin_amdgcn_mfma_f32_16x16x32_bf16(vfrag[h*2+1][0], pb0, o1, 0, 0, 0);
            o1 = __builtin_amdgcn_mfma_f32_16x16x32_bf16(vfrag[h*2+1][1], pb1, o1, 0, 0, 0);
            const unsigned q00 = pkcvt(o0[0] * inv, o0[1] * inv);
            const unsigned q01 = pkcvt(o0[2] * inv, o0[3] * inv);
            const unsigned q10 = pkcvt(o1[0] * inv, o1[1] * inv);
            const unsigned q11 = pkcvt(o1[2] * inv, o1[3] * inv);
            XCHG(bxA[mt][h], 2, q00, q01, q10, q11);
        }
    }

    // ---- Phase 4: proj (swapped) + bias + residual -> hacc[mt][ct] ----
    f32x4 hacc[4][6];
    #pragma unroll
    for (int ct = 0; ct < 6; ++ct) {
        const unsigned short* wr = wproj + (size_t)(ct * 16 + l15) * 96;
        bf16x8 wp[3];
        #pragma unroll
        for (int i = 0; i < 3; ++i) wp[i] = *(const bf16x8*)(wr + i * 32 + lk);
        const float4 pb4 = *(const float4*)(proj_b + ct * 16 + g4);
        #pragma unroll
        for (int mt = 0; mt < 4; ++mt) {
            f32x4 acc = {0.f,0.f,0.f,0.f};
            #pragma unroll
            for (int i = 0; i < 3; ++i)
                acc = __builtin_amdgcn_mfma_f32_16x16x32_bf16(wp[i], bxA[mt][i], acc, 0, 0, 0);
            const float4 xv = *(const float4*)(x + xrow[mt] + ct * 16 + g4);
            hacc[mt][ct][0] = acc[0] + pb4.x + xv.x;
            hacc[mt][ct][1] = acc[1] + pb4.y + xv.y;
            hacc[mt][ct][2] = acc[2] + pb4.z + xv.z;
            hacc[mt][ct][3] = acc[3] + pb4.w + xv.w;
        }
    }

    // ---- Phase 5: LN2 in-register per mt -> mbx[mt][kc]; fold fc2 bias into hacc ----
    bf16x8 mbx[4][3];
    #pragma unroll
    for (int mt = 0; mt < 4; ++mt) {
        float s = 0.f, ss2 = 0.f;
        #pragma unroll
        for (int ct = 0; ct < 6; ++ct)
            #pragma unroll
            for (int rr = 0; rr < 4; ++rr) { s += hacc[mt][ct][rr]; ss2 += hacc[mt][ct][rr] * hacc[mt][ct][rr]; }
        s += __shfl_xor(s, 16);  ss2 += __shfl_xor(ss2, 16);
        s += __shfl_xor(s, 32);  ss2 += __shfl_xor(ss2, 32);
        const float mean = s * (1.f / 96.f);
        const float rstd = rsqrtf(ss2 * (1.f / 96.f) - mean * mean + 1e-5f);
        #pragma unroll
        for (int kc = 0; kc < 3; ++kc) {
            const float4 g0 = *(const float4*)(ln2_g + (2*kc) * 16 + g4);
            const float4 b0 = *(const float4*)(ln2_b + (2*kc) * 16 + g4);
            const float4 g1 = *(const float4*)(ln2_g + (2*kc+1) * 16 + g4);
            const float4 b1 = *(const float4*)(ln2_b + (2*kc+1) * 16 + g4);
            const float* g0p = &g0.x; const float* b0p = &b0.x;
            const float* g1p = &g1.x; const float* b1p = &b1.x;
            float v0[4], v1[4];
            #pragma unroll
            for (int rr = 0; rr < 4; ++rr) {
                v0[rr] = (hacc[mt][2*kc][rr]   - mean) * rstd * g0p[rr] + b0p[rr];
                v1[rr] = (hacc[mt][2*kc+1][rr] - mean) * rstd * g1p[rr] + b1p[rr];
            }
            const unsigned pk00 = pkcvt(v0[0], v0[1]), pk01 = pkcvt(v0[2], v0[3]);
            const unsigned pk10 = pkcvt(v1[0], v1[1]), pk11 = pkcvt(v1[2], v1[3]);
            XCHG(mbx[mt][kc], kc, pk00, pk01, pk10, pk11);
        }
    }
    #pragma unroll
    for (int ct = 0; ct < 6; ++ct) {
        const float4 b2v = *(const float4*)(fc2_b + ct * 16 + g4);
        #pragma unroll
        for (int mt = 0; mt < 4; ++mt) {
            hacc[mt][ct][0] += b2v.x; hacc[mt][ct][1] += b2v.y;
            hacc[mt][ct][2] += b2v.z; hacc[mt][ct][3] += b2v.w;
        }
    }

    // ---- Phase 6: MLP, RUNTIME loop over 12 x 32-wide hidden chunks ----
    #pragma unroll 1
    for (int kc = 0; kc < 12; ++kc) {
        const int hb = kc * 32;
        const unsigned short* w0 = wfc1 + (size_t)(hb + l15) * 96;
        const unsigned short* w1 = wfc1 + (size_t)(hb + 16 + l15) * 96;
        bf16x8 w0f[3], w1f[3];
        #pragma unroll
        for (int i = 0; i < 3; ++i) {
            w0f[i] = *(const bf16x8*)(w0 + i * 32 + lk);
            w1f[i] = *(const bf16x8*)(w1 + i * 32 + lk);
        }
        const float4 bv0 = *(const float4*)(fc1_b + hb + g4);
        const float4 bv1 = *(const float4*)(fc1_b + hb + 16 + g4);
        const float* b0p = &bv0.x; const float* b1p = &bv1.x;
        bf16x8 pb[4];
        #pragma unroll
        for (int mt = 0; mt < 4; ++mt) {
            f32x4 s0 = {0.f,0.f,0.f,0.f}, s1 = {0.f,0.f,0.f,0.f};
            #pragma unroll
            for (int i = 0; i < 3; ++i) {
                s0 = __builtin_amdgcn_mfma_f32_16x16x32_bf16(w0f[i], mbx[mt][i], s0, 0, 0, 0);
                s1 = __builtin_amdgcn_mfma_f32_16x16x32_bf16(w1f[i], mbx[mt][i], s1, 0, 0, 0);
            }
            float ge0[4], ge1[4];
            #pragma unroll
            for (int rr = 0; rr < 4; ++rr) {
                float u = s0[rr] + b0p[rr];
                float u2 = u * u;
                float n2y = u * (-1.5957691216f - 0.0713548162f * u2);
                ge0[rr] = __fdividef(u, 1.f + __expf(n2y));
                u = s1[rr] + b1p[rr];
                u2 = u * u;
                n2y = u * (-1.5957691216f - 0.0713548162f * u2);
                ge1[rr] = __fdividef(u, 1.f + __expf(n2y));
            }
            const unsigned pk00 = pkcvt(ge0[0], ge0[1]), pk01 = pkcvt(ge0[2], ge0[3]);
            const unsigned pk10 = pkcvt(ge1[0], ge1[1]), pk11 = pkcvt(ge1[2], ge1[3]);
            XCHG(pb[mt], mt, pk00, pk01, pk10, pk11);
        }
        #pragma unroll
        for (int ct = 0; ct < 6; ++ct) {
            const bf16x8 w2f = *(const bf16x8*)(wfc2 + (size_t)(ct * 16 + l15) * 384 + hb + lk);
            #pragma unroll
            for (int mt = 0; mt < 4; ++mt)
                hacc[mt][ct] = __builtin_amdgcn_mfma_f32_16x16x32_bf16(w2f, pb[mt], hacc[mt][ct], 0, 0, 0);
        }
    }

    // ---- Phase 7: coalesced float4 stores, 4 owned token rows ----
    #pragma unroll
    for (int mt = 0; mt < 4; ++mt) {
        const int tok = mt * 16 + l15;
        if (tok < 49) {
            float* ob = out + xrow[mt];
            #pragma unroll
            for (int ct = 0; ct < 6; ++ct) {
                float4 o4;
                o4.x = hacc[mt][ct][0]; o4.y = hacc[mt][ct][1];
                o4.z = hacc[mt][ct][2]; o4.w = hacc[mt][ct][3];
                *(float4*)(ob + ct * 16 + g4) = o4;
            }
        }
    }
    #undef XCHG
}

extern "C" void kernel_launch(void* const* d_in, const int* in_sizes, int n_in,
                              void* d_out, int out_size, void* d_ws, size_t ws_size,
                              hipStream_t stream) {
    (void)n_in; (void)out_size; (void)ws_size;
    const float* x        = (const float*)d_in[0];
    const float* attn_msk = (const float*)d_in[1];
    const float* ln1_g    = (const float*)d_in[2];
    const float* ln1_b    = (const float*)d_in[3];
    const float* qkv_w    = (const float*)d_in[4];
    const float* qkv_b    = (const float*)d_in[5];
    const float* rel_tab  = (const float*)d_in[6];
    const int*   rel_idx  = (const int*)d_in[7];
    const float* proj_w   = (const float*)d_in[8];
    const float* proj_b   = (const float*)d_in[9];
    const float* ln2_g    = (const float*)d_in[10];
    const float* ln2_b    = (const float*)d_in[11];
    const float* fc1_w    = (const float*)d_in[12];
    const float* fc1_b    = (const float*)d_in[13];
    const float* fc2_w    = (const float*)d_in[14];
    const float* fc2_b    = (const float*)d_in[15];
    float* out = (float*)d_out;
    unsigned short* wsb = (unsigned short*)d_ws;
    unsigned short* bmf = wsb + 110592;

    const int B = in_sizes[0] / (3136 * 96);   // 64

    conv_w_kernel<<<(110592 + 255) / 256, 256, 0, stream>>>(qkv_w, proj_w, fc1_w, fc2_w, wsb);
    build_bmfrag_kernel<<<196608 / 256, 256, 0, stream>>>(attn_msk, rel_tab, rel_idx, bmf);

    swin_fused<<<B * 64, 64, 0, stream>>>(
        x, ln1_g, ln1_b, qkv_b, proj_b, ln2_g, ln2_b, fc1_b, fc2_b,
        wsb, wsb + 27648, wsb + 36864, wsb + 73728, bmf, out);
}